// Round 3
// baseline (2377.188 us; speedup 1.0000x reference)
//
#include <hip/hip_runtime.h>

// LightGCN forward via coarse row-bucketing + LDS-accumulated SpMM.
//   deg[i] = #edges with row==i (+1 self loop in factors)
//   a[i] = inv_sqrt*inv_deg, b[i] = inv_sqrt
//   h[r] = a[r] * ( b[r]*x[r] + sum_{e: row==r} b[c_e]*x[c_e] )
// Buckets of 256 consecutive rows; edges multi-split into buckets with
// exact per-(bucket,block) offsets so scatter writes are sequential
// per stream (L2 write-combines -> ~20MB HBM write, not 313MB).

#define D 64
#define RSHIFT 8
#define RPB 256            // rows per bucket = 1<<RSHIFT
#define NBLK_A 512         // pass-A blocks
#define SCAN_BLK 1024
#define MAXB 2048          // max buckets supported in LDS

// Pass A phase 1: per-block bucket histogram (+ global degree count)
__global__ void phase1_kernel(const int* __restrict__ rows, int* __restrict__ cnt,
                              int* __restrict__ hist, int E, int B) {
    __shared__ int lh[MAXB];
    int blk = blockIdx.x;
    int per = (E + NBLK_A - 1) / NBLK_A;
    int lo = blk * per;
    int hi = min(E, lo + per);
    for (int i = threadIdx.x; i < B; i += blockDim.x) lh[i] = 0;
    __syncthreads();
    for (int e = lo + threadIdx.x; e < hi; e += blockDim.x) {
        int r = rows[e];
        atomicAdd(&cnt[r], 1);
        atomicAdd(&lh[r >> RSHIFT], 1);
    }
    __syncthreads();
    for (int i = threadIdx.x; i < B; i += blockDim.x)
        hist[(size_t)i * NBLK_A + blk] = lh[i];
}

__global__ void factors_kernel(const int* __restrict__ cnt,
                               float* __restrict__ a, float* __restrict__ b, int n) {
    int i = blockIdx.x * blockDim.x + threadIdx.x;
    if (i >= n) return;
    float degf = (float)(cnt[i] + 1);          // +1 self loop
    float inv_deg = 1.0f / (degf + 1e-8f);
    float deg2 = degf * inv_deg;
    float inv_sqrt = rsqrtf(deg2 + 1e-8f);
    a[i] = inv_sqrt * inv_deg;
    b[i] = inv_sqrt;
}

// exclusive scan, 3 kernels, in-place on hist (length L)
__global__ void scan1_kernel(int* __restrict__ data, int* __restrict__ bsum, int L) {
    __shared__ int sm[SCAN_BLK];
    int tid = threadIdx.x;
    int i = blockIdx.x * SCAN_BLK + tid;
    int v = (i < L) ? data[i] : 0;
    sm[tid] = v;
    __syncthreads();
    for (int off = 1; off < SCAN_BLK; off <<= 1) {
        int t = (tid >= off) ? sm[tid - off] : 0;
        __syncthreads();
        sm[tid] += t;
        __syncthreads();
    }
    if (i < L) data[i] = sm[tid] - v;           // exclusive
    if (tid == SCAN_BLK - 1) bsum[blockIdx.x] = sm[tid];
}

// parallel exclusive scan of block sums (nb <= SCAN_BLK)
__global__ void scan2_kernel(int* __restrict__ bsum, int nb) {
    __shared__ int sm[SCAN_BLK];
    int tid = threadIdx.x;
    int v = (tid < nb) ? bsum[tid] : 0;
    sm[tid] = v;
    __syncthreads();
    for (int off = 1; off < SCAN_BLK; off <<= 1) {
        int t = (tid >= off) ? sm[tid - off] : 0;
        __syncthreads();
        sm[tid] += t;
        __syncthreads();
    }
    if (tid < nb) bsum[tid] = sm[tid] - v;
}

__global__ void scan3_kernel(int* __restrict__ data, const int* __restrict__ bsum, int L) {
    int i = blockIdx.x * SCAN_BLK + threadIdx.x;
    if (i < L) data[i] += bsum[blockIdx.x];
}

// Pass A phase 2: scatter packed (r_local, c) into bucket regions.
// Per-block writes to each bucket stream are sequential -> L2 write-combining.
__global__ void phase2_kernel(const int* __restrict__ rows, const int* __restrict__ cols,
                              const int* __restrict__ hist, unsigned int* __restrict__ packed,
                              int E, int B) {
    __shared__ int cur[MAXB];
    int blk = blockIdx.x;
    int per = (E + NBLK_A - 1) / NBLK_A;
    int lo = blk * per;
    int hi = min(E, lo + per);
    for (int i = threadIdx.x; i < B; i += blockDim.x)
        cur[i] = hist[(size_t)i * NBLK_A + blk];
    __syncthreads();
    for (int e = lo + threadIdx.x; e < hi; e += blockDim.x) {
        int r = rows[e];
        int c = cols[e];
        int b = r >> RSHIFT;
        int pos = atomicAdd(&cur[b], 1);
        packed[pos] = ((unsigned)(r & (RPB - 1)) << 18) | (unsigned)c;  // c < 2^18
    }
}

// Pass B: one block per bucket, LDS accumulator, coalesced x-gather.
__global__ __launch_bounds__(1024, 8)
void spmm_bucket_kernel(const unsigned int* __restrict__ packed,
                        const int* __restrict__ hist,
                        const float* __restrict__ a, const float* __restrict__ bfac,
                        const float* __restrict__ x, float* __restrict__ h,
                        int n, int E, int B) {
    __shared__ float hl[RPB * D];   // 64 KB
    int bkt = blockIdx.x;
    int start = hist[(size_t)bkt * NBLK_A];
    int end = (bkt + 1 < B) ? hist[(size_t)(bkt + 1) * NBLK_A] : E;
    for (int i = threadIdx.x; i < RPB * D; i += blockDim.x) hl[i] = 0.f;
    __syncthreads();

    int wid = threadIdx.x >> 6;
    int j = threadIdx.x & 63;
    int nw = blockDim.x >> 6;       // 16 waves
    // 2-edge unroll: two outstanding 256B gathers per wave
    for (int e = start + wid * 2; e < end; e += nw * 2) {
        unsigned w0 = packed[e];
        int c0 = (int)(w0 & 0x3FFFFu);
        int rl0 = (int)(w0 >> 18);
        float v0 = bfac[c0] * x[(size_t)c0 * D + j];
        if (e + 1 < end) {
            unsigned w1 = packed[e + 1];
            int c1 = (int)(w1 & 0x3FFFFu);
            int rl1 = (int)(w1 >> 18);
            float v1 = bfac[c1] * x[(size_t)c1 * D + j];
            atomicAdd(&hl[rl0 * D + j], v0);
            atomicAdd(&hl[rl1 * D + j], v1);
        } else {
            atomicAdd(&hl[rl0 * D + j], v0);
        }
    }
    __syncthreads();

    int r0 = bkt << RSHIFT;
    for (int idx = threadIdx.x; idx < RPB * D; idx += blockDim.x) {
        int rl = idx >> 6;
        int jj = idx & 63;
        int r = r0 + rl;
        if (r < n)
            h[(size_t)r * D + jj] = a[r] * (bfac[r] * x[(size_t)r * D + jj] + hl[idx]);
    }
}

extern "C" void kernel_launch(void* const* d_in, const int* in_sizes, int n_in,
                              void* d_out, int out_size, void* d_ws, size_t ws_size,
                              hipStream_t stream) {
    const float* x = (const float*)d_in[0];
    const int* edge = (const int*)d_in[1];
    float* h = (float*)d_out;

    int n = in_sizes[0] / D;                   // 200000
    int E = in_sizes[1] / 2;                   // 5000000
    const int* rows = edge;
    const int* cols = edge + E;

    int B = (n + RPB - 1) >> RSHIFT;           // 782 buckets
    size_t L = (size_t)B * NBLK_A;             // hist length 400384
    int NB1 = (int)((L + SCAN_BLK - 1) / SCAN_BLK);  // 391

    // ws layout: cnt[n] | a[n] | b[n] | hist[L] | bsum[NB1] | packed[E]
    char* p = (char*)d_ws;
    int* cnt        = (int*)p;        p += (size_t)n * 4;
    float* a        = (float*)p;      p += (size_t)n * 4;
    float* bfac     = (float*)p;      p += (size_t)n * 4;
    int* hist       = (int*)p;        p += L * 4;
    int* bsum       = (int*)p;        p += (size_t)NB1 * 4;
    unsigned int* packed = (unsigned int*)p;

    hipMemsetAsync(cnt, 0, (size_t)n * sizeof(int), stream);

    phase1_kernel<<<NBLK_A, 256, 0, stream>>>(rows, cnt, hist, E, B);
    factors_kernel<<<(n + 255) / 256, 256, 0, stream>>>(cnt, a, bfac, n);
    scan1_kernel<<<NB1, SCAN_BLK, 0, stream>>>(hist, bsum, (int)L);
    scan2_kernel<<<1, SCAN_BLK, 0, stream>>>(bsum, NB1);
    scan3_kernel<<<NB1, SCAN_BLK, 0, stream>>>(hist, bsum, (int)L);
    phase2_kernel<<<NBLK_A, 256, 0, stream>>>(rows, cols, hist, packed, E, B);
    spmm_bucket_kernel<<<B, 1024, 0, stream>>>(packed, hist, a, bfac, x, h, n, E, B);
}

// Round 4
// 517.126 us; speedup vs baseline: 4.5969x; 4.5969x over previous
//
#include <hip/hip_runtime.h>

// LightGCN forward: bucketed multi-split -> CSR -> gather SpMM (no output atomics).
//   deg[i] = #edges with row==i (+1 self loop in factors)
//   a[i] = inv_sqrt*inv_deg, b[i] = inv_sqrt
//   h[r] = a[r] * ( b[r]*x[r] + sum_{e: row==r} b[c_e]*x[c_e] )
// csr_fill's 313MB write amplification (random 4B scatter over 20MB) is fixed by:
//   phase2: scatter packed words into per-(bucket,block) SEQUENTIAL streams
//   sort_bucket: counting-sort within each ~25KB L2-resident bucket region

#define D 64
#define RSHIFT 8
#define RPB 256            // rows per bucket
#define NBLK_A 512         // pass-A blocks
#define SCAN_BLK 1024
#define MAXB 2048

// phase 1: per-block bucket histogram + global degree count
__global__ void phase1_kernel(const int* __restrict__ rows, int* __restrict__ cnt,
                              int* __restrict__ hist, int E, int B) {
    __shared__ int lh[MAXB];
    int blk = blockIdx.x;
    int per = (E + NBLK_A - 1) / NBLK_A;
    int lo = blk * per;
    int hi = min(E, lo + per);
    for (int i = threadIdx.x; i < B; i += blockDim.x) lh[i] = 0;
    __syncthreads();
    for (int e = lo + threadIdx.x; e < hi; e += blockDim.x) {
        int r = rows[e];
        atomicAdd(&cnt[r], 1);
        atomicAdd(&lh[r >> RSHIFT], 1);
    }
    __syncthreads();
    for (int i = threadIdx.x; i < B; i += blockDim.x)
        hist[(size_t)i * NBLK_A + blk] = lh[i];
}

__global__ void factors_kernel(const int* __restrict__ cnt,
                               float* __restrict__ a, float* __restrict__ b, int n) {
    int i = blockIdx.x * blockDim.x + threadIdx.x;
    if (i >= n) return;
    float degf = (float)(cnt[i] + 1);          // +1 self loop
    float inv_deg = 1.0f / (degf + 1e-8f);
    float deg2 = degf * inv_deg;
    float inv_sqrt = rsqrtf(deg2 + 1e-8f);
    a[i] = inv_sqrt * inv_deg;
    b[i] = inv_sqrt;
}

// exclusive scan (out-of-place ok; in==out ok), block sums -> bsum
__global__ void scan1_kernel(const int* __restrict__ in, int* __restrict__ out,
                             int* __restrict__ bsum, int L) {
    __shared__ int sm[SCAN_BLK];
    int tid = threadIdx.x;
    int i = blockIdx.x * SCAN_BLK + tid;
    int v = (i < L) ? in[i] : 0;
    sm[tid] = v;
    __syncthreads();
    for (int off = 1; off < SCAN_BLK; off <<= 1) {
        int t = (tid >= off) ? sm[tid - off] : 0;
        __syncthreads();
        sm[tid] += t;
        __syncthreads();
    }
    if (i < L) out[i] = sm[tid] - v;
    if (tid == SCAN_BLK - 1) bsum[blockIdx.x] = sm[tid];
}

__global__ void scan2_kernel(int* __restrict__ bsum, int nb) {
    __shared__ int sm[SCAN_BLK];
    int tid = threadIdx.x;
    int v = (tid < nb) ? bsum[tid] : 0;
    sm[tid] = v;
    __syncthreads();
    for (int off = 1; off < SCAN_BLK; off <<= 1) {
        int t = (tid >= off) ? sm[tid - off] : 0;
        __syncthreads();
        sm[tid] += t;
        __syncthreads();
    }
    if (tid < nb) bsum[tid] = sm[tid] - v;
}

// add block offsets; optionally write a sentinel word
__global__ void scan3_kernel(int* __restrict__ out, const int* __restrict__ bsum, int L,
                             int* sentinel_ptr, int sentinel_val) {
    int i = blockIdx.x * SCAN_BLK + threadIdx.x;
    if (i < L) out[i] += bsum[blockIdx.x];
    if (blockIdx.x == 0 && threadIdx.x == 0 && sentinel_ptr) *sentinel_ptr = sentinel_val;
}

// phase 2: scatter packed (r_local<<18 | c) into per-(bucket,block) sequential streams
__global__ void phase2_kernel(const int* __restrict__ rows, const int* __restrict__ cols,
                              const int* __restrict__ hist, unsigned int* __restrict__ packed,
                              int E, int B) {
    __shared__ int cur[MAXB];
    int blk = blockIdx.x;
    int per = (E + NBLK_A - 1) / NBLK_A;
    int lo = blk * per;
    int hi = min(E, lo + per);
    for (int i = threadIdx.x; i < B; i += blockDim.x)
        cur[i] = hist[(size_t)i * NBLK_A + blk];
    __syncthreads();
    for (int e = lo + threadIdx.x; e < hi; e += blockDim.x) {
        int r = rows[e];
        int c = cols[e];
        int b = r >> RSHIFT;
        int pos = atomicAdd(&cur[b], 1);
        packed[pos] = ((unsigned)(r & (RPB - 1)) << 18) | (unsigned)c;  // c < 2^18
    }
}

// counting sort within bucket: row_start provides exact CSR cursors.
// writes land in the bucket's ~25KB region -> L2-resident, full lines.
__global__ void sort_bucket_kernel(const unsigned int* __restrict__ packed,
                                   const int* __restrict__ hist,
                                   const int* __restrict__ row_start,
                                   int* __restrict__ col_sorted,
                                   int E, int B, int n) {
    __shared__ int cur[RPB];
    int bkt = blockIdx.x;
    int start = hist[(size_t)bkt * NBLK_A];
    int end = (bkt + 1 < B) ? hist[(size_t)(bkt + 1) * NBLK_A] : E;
    int r0 = bkt << RSHIFT;
    for (int i = threadIdx.x; i < RPB; i += blockDim.x)
        cur[i] = (r0 + i < n) ? row_start[r0 + i] : 0;
    __syncthreads();
    for (int e = start + threadIdx.x; e < end; e += blockDim.x) {
        unsigned w = packed[e];
        int rl = (int)(w >> 18);
        int pos = atomicAdd(&cur[rl], 1);
        col_sorted[pos] = (int)(w & 0x3FFFFu);
    }
}

// gather SpMM: one wave per row, lane j owns dim j, 4-wide unroll
__global__ void spmm_kernel(const int* __restrict__ row_start,
                            const int* __restrict__ col_sorted,
                            const float* __restrict__ a, const float* __restrict__ b,
                            const float* __restrict__ x, float* __restrict__ h, int n) {
    int gid = blockIdx.x * blockDim.x + threadIdx.x;
    int r = gid >> 6;
    int j = gid & 63;
    if (r >= n) return;
    int s = row_start[r];
    int e = row_start[r + 1];
    float acc0 = b[r] * x[(size_t)r * D + j];   // self loop
    float acc1 = 0.f, acc2 = 0.f, acc3 = 0.f;
    int k = s;
    for (; k + 3 < e; k += 4) {
        int c0 = col_sorted[k];
        int c1 = col_sorted[k + 1];
        int c2 = col_sorted[k + 2];
        int c3 = col_sorted[k + 3];
        acc0 += b[c0] * x[(size_t)c0 * D + j];
        acc1 += b[c1] * x[(size_t)c1 * D + j];
        acc2 += b[c2] * x[(size_t)c2 * D + j];
        acc3 += b[c3] * x[(size_t)c3 * D + j];
    }
    for (; k < e; ++k) {
        int c = col_sorted[k];
        acc0 += b[c] * x[(size_t)c * D + j];
    }
    h[(size_t)r * D + j] = a[r] * ((acc0 + acc1) + (acc2 + acc3));
}

extern "C" void kernel_launch(void* const* d_in, const int* in_sizes, int n_in,
                              void* d_out, int out_size, void* d_ws, size_t ws_size,
                              hipStream_t stream) {
    const float* x = (const float*)d_in[0];
    const int* edge = (const int*)d_in[1];
    float* h = (float*)d_out;

    int n = in_sizes[0] / D;                   // 200000
    int E = in_sizes[1] / 2;                   // 5000000
    const int* rows = edge;
    const int* cols = edge + E;

    int B = (n + RPB - 1) >> RSHIFT;           // 782
    size_t L = (size_t)B * NBLK_A;             // 400384
    int NB_H = (int)((L + SCAN_BLK - 1) / SCAN_BLK);   // 391
    int NB_R = (n + SCAN_BLK - 1) / SCAN_BLK;          // 196

    // ws: cnt[n] | row_start[n+1] | a[n] | b[n] | hist[L] | bsumA[1024] | bsumB[1024]
    //     | packed[E] | col_sorted[E]   (~46 MB)
    char* p = (char*)d_ws;
    int* cnt        = (int*)p;        p += (size_t)n * 4;
    int* row_start  = (int*)p;        p += (size_t)(n + 1) * 4;
    float* a        = (float*)p;      p += (size_t)n * 4;
    float* bfac     = (float*)p;      p += (size_t)n * 4;
    int* hist       = (int*)p;        p += L * 4;
    int* bsumA      = (int*)p;        p += (size_t)SCAN_BLK * 4;
    int* bsumB      = (int*)p;        p += (size_t)SCAN_BLK * 4;
    unsigned int* packed = (unsigned int*)p;  p += (size_t)E * 4;
    int* col_sorted = (int*)p;

    hipMemsetAsync(cnt, 0, (size_t)n * sizeof(int), stream);

    phase1_kernel<<<NBLK_A, 256, 0, stream>>>(rows, cnt, hist, E, B);
    factors_kernel<<<(n + 255) / 256, 256, 0, stream>>>(cnt, a, bfac, n);

    // scan hist (in place)
    scan1_kernel<<<NB_H, SCAN_BLK, 0, stream>>>(hist, hist, bsumA, (int)L);
    scan2_kernel<<<1, SCAN_BLK, 0, stream>>>(bsumA, NB_H);
    scan3_kernel<<<NB_H, SCAN_BLK, 0, stream>>>(hist, bsumA, (int)L, nullptr, 0);

    // scan cnt -> row_start, sentinel row_start[n]=E
    scan1_kernel<<<NB_R, SCAN_BLK, 0, stream>>>(cnt, row_start, bsumB, n);
    scan2_kernel<<<1, SCAN_BLK, 0, stream>>>(bsumB, NB_R);
    scan3_kernel<<<NB_R, SCAN_BLK, 0, stream>>>(row_start, bsumB, n, row_start + n, E);

    phase2_kernel<<<NBLK_A, 256, 0, stream>>>(rows, cols, hist, packed, E, B);
    sort_bucket_kernel<<<B, 512, 0, stream>>>(packed, hist, row_start, col_sorted, E, B, n);
    spmm_kernel<<<(n * D + 255) / 256, 256, 0, stream>>>(row_start, col_sorted, a, bfac, x, h, n);
}

// Round 5
// 320.117 us; speedup vs baseline: 7.4260x; 1.6154x over previous
//
#include <hip/hip_runtime.h>

// LightGCN forward: bucketed multi-split -> in-place bucket sort -> bf16 gather SpMM.
//   deg[i] = #edges with row==i (+1 self loop in factors)
//   a[i] = inv_sqrt*inv_deg, b[i] = inv_sqrt   (deg2 = deg/(deg+1e-8) ~= 1)
//   y[i,:] = b[i]*x[i,:]  stored bf16 (halves gather traffic)
//   h[r] = a[r] * ( y[r] + sum_{e: row==r} y[c_e] )
// CSR build: phase1 bucket hist -> scan -> phase2 sequential-stream scatter of
// packed (r_local<<18|c) -> sort_bucket stages bucket in LDS, counts rows,
// scans, writes row_start + factors, scatters cols back IN PLACE over packed.

#define D 64
#define RSHIFT 8
#define RPB 256            // rows per bucket
#define NBLK_A 512         // pass-A blocks
#define SCAN_BLK 1024
#define MAXB 2048
#define SORT_CAP 15104     // bucket edges stageable in LDS (60416 B)

typedef unsigned short ushort_t;

__device__ __forceinline__ float bf2f(ushort_t v) {
    return __uint_as_float(((unsigned)v) << 16);
}
__device__ __forceinline__ ushort_t f2bf(float f) {   // round-to-nearest-even
    unsigned u = __float_as_uint(f);
    unsigned r = (u + 0x7FFFu + ((u >> 16) & 1u)) >> 16;
    return (ushort_t)r;
}

// phase 1: per-block bucket histogram only
__global__ void phase1_kernel(const int* __restrict__ rows,
                              int* __restrict__ hist, int E, int B) {
    __shared__ int lh[MAXB];
    int blk = blockIdx.x;
    int per = (E + NBLK_A - 1) / NBLK_A;
    int lo = blk * per;
    int hi = min(E, lo + per);
    for (int i = threadIdx.x; i < B; i += blockDim.x) lh[i] = 0;
    __syncthreads();
    for (int e = lo + threadIdx.x; e < hi; e += blockDim.x)
        atomicAdd(&lh[rows[e] >> RSHIFT], 1);
    __syncthreads();
    for (int i = threadIdx.x; i < B; i += blockDim.x)
        hist[(size_t)i * NBLK_A + blk] = lh[i];
}

// exclusive scan over hist (3 kernels)
__global__ void scan1_kernel(const int* __restrict__ in, int* __restrict__ out,
                             int* __restrict__ bsum, int L) {
    __shared__ int sm[SCAN_BLK];
    int tid = threadIdx.x;
    int i = blockIdx.x * SCAN_BLK + tid;
    int v = (i < L) ? in[i] : 0;
    sm[tid] = v;
    __syncthreads();
    for (int off = 1; off < SCAN_BLK; off <<= 1) {
        int t = (tid >= off) ? sm[tid - off] : 0;
        __syncthreads();
        sm[tid] += t;
        __syncthreads();
    }
    if (i < L) out[i] = sm[tid] - v;
    if (tid == SCAN_BLK - 1) bsum[blockIdx.x] = sm[tid];
}

__global__ void scan2_kernel(int* __restrict__ bsum, int nb) {
    __shared__ int sm[SCAN_BLK];
    int tid = threadIdx.x;
    int v = (tid < nb) ? bsum[tid] : 0;
    sm[tid] = v;
    __syncthreads();
    for (int off = 1; off < SCAN_BLK; off <<= 1) {
        int t = (tid >= off) ? sm[tid - off] : 0;
        __syncthreads();
        sm[tid] += t;
        __syncthreads();
    }
    if (tid < nb) bsum[tid] = sm[tid] - v;
}

__global__ void scan3_kernel(int* __restrict__ out, const int* __restrict__ bsum, int L,
                             int* sentinel_ptr, int sentinel_val) {
    int i = blockIdx.x * SCAN_BLK + threadIdx.x;
    if (i < L) out[i] += bsum[blockIdx.x];
    if (blockIdx.x == 0 && threadIdx.x == 0 && sentinel_ptr) *sentinel_ptr = sentinel_val;
}

// phase 2: scatter packed (r_local<<18 | c) into per-(bucket,block) sequential streams
__global__ void phase2_kernel(const int* __restrict__ rows, const int* __restrict__ cols,
                              const int* __restrict__ hist, unsigned int* __restrict__ packed,
                              int E, int B) {
    __shared__ int cur[MAXB];
    int blk = blockIdx.x;
    int per = (E + NBLK_A - 1) / NBLK_A;
    int lo = blk * per;
    int hi = min(E, lo + per);
    for (int i = threadIdx.x; i < B; i += blockDim.x)
        cur[i] = hist[(size_t)i * NBLK_A + blk];
    __syncthreads();
    for (int e = lo + threadIdx.x; e < hi; e += blockDim.x) {
        int r = rows[e];
        int c = cols[e];
        int pos = atomicAdd(&cur[r >> RSHIFT], 1);
        packed[pos] = ((unsigned)(r & (RPB - 1)) << 18) | (unsigned)c;
    }
}

// sort_bucket: stage bucket in LDS, per-row count, scan -> row_start + factors,
// scatter cols back IN PLACE over packed (bucket CSR region == bucket region).
__global__ __launch_bounds__(RPB)
void sort_bucket_kernel(unsigned int* __restrict__ packed,
                        const int* __restrict__ hist,
                        int* __restrict__ row_start,
                        float* __restrict__ afac, float* __restrict__ bfac,
                        unsigned int* __restrict__ scratch,  // fallback only
                        int E, int B, int n) {
    __shared__ unsigned int buf[SORT_CAP];
    __shared__ int cnt[RPB];
    __shared__ int scn[RPB];
    __shared__ int cur[RPB];
    int bkt = blockIdx.x;
    int start = hist[(size_t)bkt * NBLK_A];
    int end = (bkt + 1 < B) ? hist[(size_t)(bkt + 1) * NBLK_A] : E;
    int m = end - start;
    int tid = threadIdx.x;
    int r0 = bkt << RSHIFT;

    cnt[tid] = 0;
    __syncthreads();

    bool lds_path = (m <= SORT_CAP);
    if (lds_path) {
        for (int k = tid; k < m; k += RPB) {
            unsigned w = packed[start + k];
            buf[k] = w;
            atomicAdd(&cnt[w >> 18], 1);
        }
    } else {
        for (int k = tid; k < m; k += RPB) {
            unsigned w = packed[start + k];
            scratch[start + k] = w;
            atomicAdd(&cnt[w >> 18], 1);
        }
        __threadfence();
    }
    __syncthreads();

    // exclusive scan of cnt (256 entries, Hillis-Steele)
    int v = cnt[tid];
    scn[tid] = v;
    __syncthreads();
    for (int off = 1; off < RPB; off <<= 1) {
        int t = (tid >= off) ? scn[tid - off] : 0;
        __syncthreads();
        scn[tid] += t;
        __syncthreads();
    }
    int excl = scn[tid] - v;
    cur[tid] = start + excl;     // global cursor
    int r = r0 + tid;
    if (r < n) {
        row_start[r] = start + excl;
        float degf = (float)(v + 1);             // +1 self loop
        float inv_deg = 1.0f / (degf + 1e-8f);
        float deg2 = degf * inv_deg;
        float inv_sqrt = rsqrtf(deg2 + 1e-8f);
        afac[r] = inv_sqrt * inv_deg;
        bfac[r] = inv_sqrt;
    }
    __syncthreads();

    if (lds_path) {
        for (int k = tid; k < m; k += RPB) {
            unsigned w = buf[k];
            int pos = atomicAdd(&cur[w >> 18], 1);
            packed[pos] = w & 0x3FFFFu;
        }
    } else {
        for (int k = tid; k < m; k += RPB) {
            unsigned w = scratch[start + k];
            int pos = atomicAdd(&cur[w >> 18], 1);
            packed[pos] = w & 0x3FFFFu;
        }
    }
}

// y = b*x in bf16, 4 elems/thread
__global__ void convert_kernel(const float* __restrict__ x, const float* __restrict__ bfac,
                               ushort_t* __restrict__ y, int n) {
    int t = blockIdx.x * blockDim.x + threadIdx.x;
    int total = n * (D / 4);
    if (t >= total) return;
    int i = t * 4;
    float b = bfac[i >> 6];
    const float4 xv = *reinterpret_cast<const float4*>(&x[i]);
    ushort4 o;
    o.x = f2bf(b * xv.x);
    o.y = f2bf(b * xv.y);
    o.z = f2bf(b * xv.z);
    o.w = f2bf(b * xv.w);
    *reinterpret_cast<ushort4*>(&y[i]) = o;
}

// gather SpMM: one wave per row, lane j owns dim j, 4-wide unroll, bf16 gather
__global__ void spmm_kernel(const int* __restrict__ row_start,
                            const unsigned int* __restrict__ cols,   // sorted, in packed
                            const float* __restrict__ afac,
                            const ushort_t* __restrict__ y,
                            float* __restrict__ h, int n) {
    int gid = blockIdx.x * blockDim.x + threadIdx.x;
    int r = gid >> 6;
    int j = gid & 63;
    if (r >= n) return;
    int s = row_start[r];
    int e = row_start[r + 1];
    float acc0 = bf2f(y[(size_t)r * D + j]);     // self loop (b[r]*x[r])
    float acc1 = 0.f, acc2 = 0.f, acc3 = 0.f;
    int k = s;
    for (; k + 3 < e; k += 4) {
        int c0 = (int)cols[k];
        int c1 = (int)cols[k + 1];
        int c2 = (int)cols[k + 2];
        int c3 = (int)cols[k + 3];
        acc0 += bf2f(y[(size_t)c0 * D + j]);
        acc1 += bf2f(y[(size_t)c1 * D + j]);
        acc2 += bf2f(y[(size_t)c2 * D + j]);
        acc3 += bf2f(y[(size_t)c3 * D + j]);
    }
    for (; k < e; ++k) {
        int c = (int)cols[k];
        acc0 += bf2f(y[(size_t)c * D + j]);
    }
    h[(size_t)r * D + j] = afac[r] * ((acc0 + acc1) + (acc2 + acc3));
}

extern "C" void kernel_launch(void* const* d_in, const int* in_sizes, int n_in,
                              void* d_out, int out_size, void* d_ws, size_t ws_size,
                              hipStream_t stream) {
    const float* x = (const float*)d_in[0];
    const int* edge = (const int*)d_in[1];
    float* h = (float*)d_out;

    int n = in_sizes[0] / D;                   // 200000
    int E = in_sizes[1] / 2;                   // 5000000
    const int* rows = edge;
    const int* cols = edge + E;

    int B = (n + RPB - 1) >> RSHIFT;           // 782
    size_t L = (size_t)B * NBLK_A;             // 400384
    int NB_H = (int)((L + SCAN_BLK - 1) / SCAN_BLK);   // 391

    // ws: hist[L] | bsum[1024] | row_start[n+1] | afac[n] | bfac[n] | packed[E] | y[n*64]
    //  (~50 MB; y region doubles as sort fallback scratch, used before y is written)
    char* p = (char*)d_ws;
    int* hist       = (int*)p;        p += L * 4;
    int* bsum       = (int*)p;        p += (size_t)SCAN_BLK * 4;
    int* row_start  = (int*)p;        p += (size_t)(n + 1) * 4;
    float* afac     = (float*)p;      p += (size_t)n * 4;
    float* bfac     = (float*)p;      p += (size_t)n * 4;
    unsigned int* packed = (unsigned int*)p;  p += (size_t)E * 4;
    ushort_t* y     = (ushort_t*)p;

    phase1_kernel<<<NBLK_A, 256, 0, stream>>>(rows, hist, E, B);

    scan1_kernel<<<NB_H, SCAN_BLK, 0, stream>>>(hist, hist, bsum, (int)L);
    scan2_kernel<<<1, SCAN_BLK, 0, stream>>>(bsum, NB_H);
    scan3_kernel<<<NB_H, SCAN_BLK, 0, stream>>>(hist, bsum, (int)L, row_start + n, E);

    phase2_kernel<<<NBLK_A, 256, 0, stream>>>(rows, cols, hist, packed, E, B);
    sort_bucket_kernel<<<B, RPB, 0, stream>>>(packed, hist, row_start, afac, bfac,
                                              (unsigned int*)y, E, B, n);
    convert_kernel<<<(n * (D / 4) + 255) / 256, 256, 0, stream>>>(x, bfac, y, n);
    spmm_kernel<<<(n * D + 255) / 256, 256, 0, stream>>>(row_start, packed, afac, y, h, n);
}